// Round 14
// baseline (1301.600 us; speedup 1.0000x reference)
//
#include <hip/hip_runtime.h>
#include <hip/hip_bf16.h>
#include <stdint.h>

#define TT 4096
#define HH 4096
#define FF 14336
#define NCAT (2 * FF)   // 28672

typedef __attribute__((ext_vector_type(8))) short bf16x8;
typedef __attribute__((ext_vector_type(4))) float f32x4;

__device__ __forceinline__ unsigned short f32_to_bf16(float f) {
    union { float f; unsigned int u; } v; v.f = f;
    unsigned int r = v.u + 0x7FFFu + ((v.u >> 16) & 1u);  // RNE
    return (unsigned short)(r >> 16);
}

#define GLOAD16(g, l)                                                          \
    __builtin_amdgcn_global_load_lds(                                          \
        (const __attribute__((address_space(1))) void*)(g),                    \
        (__attribute__((address_space(3))) void*)(l), 16, 0, 0)

// ---------------- convert fp32 -> bf16, same layout ----------------
__global__ void cvt_lin(const float* __restrict__ in,
                        unsigned short* __restrict__ out, long n4) {
    long stride = (long)gridDim.x * blockDim.x;
    for (long i = (long)blockIdx.x * blockDim.x + threadIdx.x; i < n4; i += stride) {
        float4 v = *(const float4*)(in + i * 4);
        ushort4 o;
        o.x = f32_to_bf16(v.x); o.y = f32_to_bf16(v.y);
        o.z = f32_to_bf16(v.z); o.w = f32_to_bf16(v.w);
        *(ushort4*)(out + i * 4) = o;
    }
}

// ---- convert + transpose + interleave: in [H][F] fp32 -> wcat rows bf16 ----
// f-column f of `in` goes to wcat row ((f>>4)<<5) + (f&15) + off (off=0 gate,
// 16 up): 16-col interleave matching the 16x16 MFMA epilogue pairing.
__global__ void cvt_tri(const float* __restrict__ in,
                        unsigned short* __restrict__ out, int off) {
    __shared__ float tile[64][65];
    int bh = blockIdx.x & 63;   // H/64 = 64
    int bf = blockIdx.x >> 6;   // F/64 = 224
    int t = threadIdx.x;
    int r16 = t >> 4;           // 0..15
    int c4 = (t & 15) * 4;      // 0..60
#pragma unroll
    for (int it = 0; it < 4; ++it) {
        int h = r16 + it * 16;
        float4 v = *(const float4*)(in + (size_t)(bh * 64 + h) * FF + bf * 64 + c4);
        tile[h][c4 + 0] = v.x; tile[h][c4 + 1] = v.y;
        tile[h][c4 + 2] = v.z; tile[h][c4 + 3] = v.w;
    }
    __syncthreads();
#pragma unroll
    for (int it = 0; it < 4; ++it) {
        int f = r16 + it * 16;
        int fg = bf * 64 + f;
        int row_out = ((fg >> 4) << 5) + (fg & 15) + off;
        ushort4 o;
        o.x = f32_to_bf16(tile[c4 + 0][f]);
        o.y = f32_to_bf16(tile[c4 + 1][f]);
        o.z = f32_to_bf16(tile[c4 + 2][f]);
        o.w = f32_to_bf16(tile[c4 + 3][f]);
        *(ushort4*)(out + (size_t)row_out * HH + bh * 64 + c4) = o;
    }
}

// ============ 2-region 256x256 GEMM core (BK=64, 8 waves) ==================
// r14: 2 barriers/K-step, 32-MFMA clusters, RACE-SAFE by construction.
// r13's failure: cross-wave races — (a) prefetch read data staged 0.5 K-step
// earlier with no universal-drain+barrier; (b) stage into a slot other waves
// read in the SAME barrier region.  Safety rule used here:
//   WAR: stage only into slots read+consumed in a PREVIOUS region.
//   RAW: read only data whose batch was drained by EVERY wave's vmcnt fence
//        followed by a barrier.
// Region map, K-step tau on buffer B (other OB):
//  R1: read B.A0(8)+B.B0(4)+B.B1(4); stage OB.A1<-tau+1 (2);
//      MFMA m0n0,m0n1 (32); F1=vmcnt(8) [drains R1(tau-1)'s 2]; BAR.
//  R2: read B.A1(8, af in-place); stage B.{A0,B0,B1}<-tau+2 (6);
//      MFMA m1n1,m1n0 (32); F2=vmcnt(8) [drains R2(tau-1)'s 6]; BAR.
// WAR ledger: A0/B0/B1 read+consumed R1 -> staged R2 (1 barrier later);
//   A1 read+consumed R2 -> staged next R1 (1 barrier later).  All consumption
//   is lgkmcnt-before-MFMA, before the wave's barrier arrival.
// RAW ledger: R1(tau) reads tile tau {A0,B0,B1} staged R2(tau-2), drained by
//   F2(tau-1)+BAR-end(tau-1) universally; R2(tau) reads A1 staged R1(tau-1),
//   drained by F1(tau)+BAR-mid(tau).  Fences are 1 K-step after issue -> no
//   stall.  Registers: af 32 + bfA 16 + bfB 16 held; acc 128 AGPR.
// Swizzle byte ^= ((row&6)<<4): pre-swizzled gload SOURCE + XOR on ds_read.

#define STG_A(BUF, SLOT, T) do {                                               \
    char* d_ = (char*)smem + (((BUF)*2 + (SLOT)) << 14) + tid * 16;            \
    GLOAD16(Abase + ((size_t)oA[SLOT] + (size_t)(T) * 128), d_);               \
    GLOAD16(Abase + ((size_t)oA[SLOT] + CA + (size_t)(T) * 128), d_ + 8192);   \
  } while (0)

#define STG_B(BUF, SLOT, T) do {                                               \
    char* d_ = (char*)smem + 65536 + (((BUF)*2 + (SLOT)) << 14) + tid * 16;    \
    GLOAD16(Bbase + ((size_t)oB[SLOT] + (size_t)(T) * 128), d_);               \
    GLOAD16(Bbase + ((size_t)oB[SLOT] + CB + (size_t)(T) * 128), d_ + 8192);   \
  } while (0)

#define READ_A(DST, BUF, MQ) do {                                              \
    const char* pA_ = (const char*)smem + (((BUF)*2 + (MQ)) << 14);            \
    _Pragma("unroll") for (int i_ = 0; i_ < 4; ++i_)                           \
    _Pragma("unroll") for (int k_ = 0; k_ < 2; ++k_)                           \
      DST[i_][k_] = *(const bf16x8*)(pA_ + ((((wr*64 + i_*16 + fr) << 7) + k_*64 + kg2) ^ lmask)); \
  } while (0)

#define READ_B(DST, BUF, NQ) do {                                              \
    const char* pB_ = (const char*)smem + 65536 + (((BUF)*2 + (NQ)) << 14);    \
    _Pragma("unroll") for (int j_ = 0; j_ < 2; ++j_)                           \
    _Pragma("unroll") for (int k_ = 0; k_ < 2; ++k_)                           \
      DST[j_][k_] = *(const bf16x8*)(pB_ + ((((wc*32 + j_*16 + fr) << 7) + k_*64 + kg2) ^ lmask)); \
  } while (0)

#define MFMA_Q(MQ, NQ, AF, BF)                                                 \
    _Pragma("unroll") for (int i_ = 0; i_ < 4; ++i_)                           \
    _Pragma("unroll") for (int j_ = 0; j_ < 2; ++j_)                           \
    _Pragma("unroll") for (int k_ = 0; k_ < 2; ++k_)                           \
      acc[MQ][i_][NQ][j_] = __builtin_amdgcn_mfma_f32_16x16x32_bf16(           \
          AF[i_][k_], BF[j_][k_], acc[MQ][i_][NQ][j_], 0, 0, 0)

#define BAR do {                                                               \
    asm volatile("" ::: "memory");                                             \
    __builtin_amdgcn_s_barrier();                                              \
    asm volatile("" ::: "memory");                                             \
  } while (0)

#define VMC8 asm volatile("s_waitcnt vmcnt(8)" ::: "memory")
#define VMC6 asm volatile("s_waitcnt vmcnt(6)" ::: "memory")
#define VMC0 asm volatile("s_waitcnt vmcnt(0)" ::: "memory")

// Steady K-step on tile TAU, buffer BUF (other OB).
#define KSTEP(BUF, OB, TAU)                                                    \
    READ_A(af, BUF, 0);                                                        \
    READ_B(bfA, BUF, 0);                                                       \
    READ_B(bfB, BUF, 1);                                                       \
    STG_A(OB, 1, (TAU) + 1);                                                   \
    __builtin_amdgcn_s_setprio(1);                                             \
    MFMA_Q(0, 0, af, bfA);                                                     \
    MFMA_Q(0, 1, af, bfB);                                                     \
    __builtin_amdgcn_s_setprio(0);                                             \
    VMC8;                                                                      \
    BAR;                                                                       \
    READ_A(af, BUF, 1);                                                        \
    STG_A(BUF, 0, (TAU) + 2); STG_B(BUF, 0, (TAU) + 2); STG_B(BUF, 1, (TAU) + 2); \
    __builtin_amdgcn_s_setprio(1);                                             \
    MFMA_Q(1, 1, af, bfB);                                                     \
    MFMA_Q(1, 0, af, bfA);                                                     \
    __builtin_amdgcn_s_setprio(0);                                             \
    VMC8;                                                                      \
    BAR;

// Tail K-step NT-2: R1 stages OB.A1<-NT-1 (last needed stage); R2 no stage,
// full drain (covers buf(NT-1)'s {A0,B0,B1} staged at R2(NT-3) and A1 here).
#define KSTEP_T1(BUF, OB, TAU)                                                 \
    READ_A(af, BUF, 0);                                                        \
    READ_B(bfA, BUF, 0);                                                       \
    READ_B(bfB, BUF, 1);                                                       \
    STG_A(OB, 1, (TAU) + 1);                                                   \
    __builtin_amdgcn_s_setprio(1);                                             \
    MFMA_Q(0, 0, af, bfA);                                                     \
    MFMA_Q(0, 1, af, bfB);                                                     \
    __builtin_amdgcn_s_setprio(0);                                             \
    VMC8;                                                                      \
    BAR;                                                                       \
    READ_A(af, BUF, 1);                                                        \
    __builtin_amdgcn_s_setprio(1);                                             \
    MFMA_Q(1, 1, af, bfB);                                                     \
    MFMA_Q(1, 0, af, bfA);                                                     \
    __builtin_amdgcn_s_setprio(0);                                             \
    VMC0;                                                                      \
    BAR;

// Final K-step: pure compute (everything already drained by T1's VMC0).
#define KSTEP_T2(BUF)                                                          \
    READ_A(af, BUF, 0);                                                        \
    READ_B(bfA, BUF, 0);                                                       \
    READ_B(bfB, BUF, 1);                                                       \
    MFMA_Q(0, 0, af, bfA);                                                     \
    MFMA_Q(0, 1, af, bfB);                                                     \
    BAR;                                                                       \
    READ_A(af, BUF, 1);                                                        \
    MFMA_Q(1, 1, af, bfB);                                                     \
    MFMA_Q(1, 0, af, bfA);

#define GEMM8_CORE(A_, LDA_, B_, LDB_, NT_)                                    \
  extern __shared__ char smem[];                                               \
  const char* const Abase = (const char*)(A_);                                 \
  const char* const Bbase = (const char*)(B_);                                 \
  const size_t CA = (size_t)(LDA_) * 256;                                      \
  const size_t CB = (size_t)(LDB_) * 256;                                      \
  const int tid = threadIdx.x;                                                 \
  const int lane = tid & 63;                                                   \
  const int wid = tid >> 6;                                                    \
  const int wr = wid >> 2;                                                     \
  const int wc = wid & 3;                                                      \
  const int fr = lane & 15;                                                    \
  const int kg2 = ((lane >> 4) & 3) << 4;                                      \
  const int lmask = (fr & 6) << 4;                                             \
  f32x4 acc[2][4][2][2];                                                       \
  _Pragma("unroll") for (int a_ = 0; a_ < 2; ++a_)                             \
  _Pragma("unroll") for (int b_ = 0; b_ < 4; ++b_)                             \
  _Pragma("unroll") for (int c_ = 0; c_ < 2; ++c_)                             \
  _Pragma("unroll") for (int d_ = 0; d_ < 2; ++d_)                             \
    acc[a_][b_][c_][d_] = (f32x4){0.f, 0.f, 0.f, 0.f};                         \
  bf16x8 af[4][2], bfA[2][2], bfB[2][2];                                       \
  unsigned int oA[2], oB[2];                                                   \
  {                                                                            \
    int d_ = tid * 16;                                                         \
    int p_ = d_ ^ (((d_ >> 8) & 3) << 5);                                      \
    int prow = p_ >> 7, pcol = (p_ & 127) >> 1;                                \
    _Pragma("unroll") for (int s_ = 0; s_ < 2; ++s_) {                         \
      int grA = m0 + s_ * 64 + (prow & 63);                                    \
      oA[s_] = (unsigned)((size_t)grA * (LDA_) + pcol) * 2u;                   \
      int grB = n0 + (prow >> 5) * 64 + s_ * 32 + (prow & 31);                 \
      oB[s_] = (unsigned)((size_t)grB * (LDB_) + pcol) * 2u;                   \
    }                                                                          \
  }                                                                            \
  /* prologue: buf0 full tile0 (8) + buf1 {A0,B0,B1} tile1 (6); vmcnt(6) */    \
  /* drains buf0's 8 (universal, pre-barrier); buf1.A1 staged at R1(0). */     \
  STG_A(0, 0, 0); STG_B(0, 0, 0); STG_B(0, 1, 0); STG_A(0, 1, 0);              \
  STG_A(1, 0, 1); STG_B(1, 0, 1); STG_B(1, 1, 1);                              \
  VMC6;                                                                        \
  __builtin_amdgcn_s_barrier();                                                \
  asm volatile("" ::: "memory");                                               \
  const int niter = (NT_) / 2;                                                 \
  for (int I = 0; I < niter - 1; ++I) {                                        \
    KSTEP(0, 1, 2 * I)                                                         \
    KSTEP(1, 0, 2 * I + 1)                                                     \
  }                                                                            \
  KSTEP_T1(0, 1, (NT_) - 2)                                                    \
  KSTEP_T2(1)

// ---------------- GEMM1: acc = Xb @ Wcat^T, fused SwiGLU epilogue ----------
__global__ __launch_bounds__(512)
__attribute__((amdgpu_waves_per_eu(1, 2))) void gemm_swiglu(
    const unsigned short* __restrict__ Xb,
    const unsigned short* __restrict__ Wcat,
    unsigned short* __restrict__ Act) {
    int lid = blockIdx.x;
    const int m0 = (lid & 15) * 256;   // tm fast
    const int n0 = (lid >> 4) * 256;

    GEMM8_CORE(Xb, HH, Wcat, HH, HH / 64)

    const int dm = ((lane >> 4) & 3) * 4;
    const int dn = lane & 15;
#pragma unroll
    for (int mq = 0; mq < 2; ++mq)
#pragma unroll
        for (int i = 0; i < 4; ++i)
#pragma unroll
            for (int nq = 0; nq < 2; ++nq) {
                int rowb = m0 + wr * 128 + mq * 64 + i * 16 + dm;
                int col = (n0 + wc * 64 + nq * 32) / 2 + dn;
                f32x4 g4 = acc[mq][i][nq][0];
                f32x4 u4 = acc[mq][i][nq][1];
#pragma unroll
                for (int r = 0; r < 4; ++r) {
                    float g = g4[r], u = u4[r];
                    float s = g * u / (1.0f + __expf(-g));
                    Act[(size_t)(rowb + r) * FF + col] = f32_to_bf16(s);
                }
            }
}

// ---------------- GEMM2: Out = Act @ W2b^T ----------------------------------
__global__ __launch_bounds__(512)
__attribute__((amdgpu_waves_per_eu(1, 2))) void gemm_down(
    const unsigned short* __restrict__ Act,
    const unsigned short* __restrict__ W2b,
    float* __restrict__ Out) {
    int lid = blockIdx.x;
    const int m0 = (lid & 15) * 256;
    const int n0 = (lid >> 4) * 256;

    GEMM8_CORE(Act, FF, W2b, FF, FF / 64)

    const int dm = ((lane >> 4) & 3) * 4;
    const int dn = lane & 15;
#pragma unroll
    for (int mq = 0; mq < 2; ++mq)
#pragma unroll
        for (int i = 0; i < 4; ++i)
#pragma unroll
            for (int nq = 0; nq < 2; ++nq)
#pragma unroll
                for (int j = 0; j < 2; ++j) {
                    int rowb = m0 + wr * 128 + mq * 64 + i * 16 + dm;
                    int col = n0 + wc * 64 + nq * 32 + j * 16 + dn;
                    f32x4 v = acc[mq][i][nq][j];
#pragma unroll
                    for (int r = 0; r < 4; ++r)
                        Out[(size_t)(rowb + r) * HH + col] = v[r];
                }
}

extern "C" void kernel_launch(void* const* d_in, const int* in_sizes, int n_in,
                              void* d_out, int out_size, void* d_ws, size_t ws_size,
                              hipStream_t stream) {
    const float* x  = (const float*)d_in[0];
    const float* w1 = (const float*)d_in[1];
    const float* v1 = (const float*)d_in[2];
    const float* w2 = (const float*)d_in[3];
    float* out = (float*)d_out;

    unsigned short* xb   = (unsigned short*)d_ws;               // [T][H]
    unsigned short* wcat = xb + (size_t)TT * HH;                // [2F][H]
    unsigned short* w2b  = wcat + (size_t)NCAT * HH;            // [H][F]
    unsigned short* act  = w2b + (size_t)HH * FF;               // [T][F]

    hipFuncSetAttribute((const void*)gemm_swiglu,
                        hipFuncAttributeMaxDynamicSharedMemorySize, 131072);
    hipFuncSetAttribute((const void*)gemm_down,
                        hipFuncAttributeMaxDynamicSharedMemorySize, 131072);

    cvt_lin<<<2048, 256, 0, stream>>>(x, xb, (long)TT * HH / 4);
    cvt_lin<<<2048, 256, 0, stream>>>(w2, w2b, (long)HH * FF / 4);
    cvt_tri<<<(HH / 64) * (FF / 64), 256, 0, stream>>>(w1, wcat, 0);
    cvt_tri<<<(HH / 64) * (FF / 64), 256, 0, stream>>>(v1, wcat, 16);

    gemm_swiglu<<<(TT / 256) * (NCAT / 256), 512, 131072, stream>>>(xb, wcat, act);
    gemm_down<<<(TT / 256) * (HH / 256), 512, 131072, stream>>>(act, w2b, out);
}

// Round 15
// 1279.280 us; speedup vs baseline: 1.0174x; 1.0174x over previous
//
#include <hip/hip_runtime.h>
#include <hip/hip_bf16.h>
#include <stdint.h>

#define TT 4096
#define HH 4096
#define FF 14336
#define NCAT (2 * FF)   // 28672

typedef __attribute__((ext_vector_type(8))) short bf16x8;
typedef __attribute__((ext_vector_type(4))) float f32x4;

__device__ __forceinline__ unsigned short f32_to_bf16(float f) {
    union { float f; unsigned int u; } v; v.f = f;
    unsigned int r = v.u + 0x7FFFu + ((v.u >> 16) & 1u);  // RNE
    return (unsigned short)(r >> 16);
}

#define GLOAD16(g, l)                                                          \
    __builtin_amdgcn_global_load_lds(                                          \
        (const __attribute__((address_space(1))) void*)(g),                    \
        (__attribute__((address_space(3))) void*)(l), 16, 0, 0)

// ---------------- convert fp32 -> bf16, same layout ----------------
__global__ void cvt_lin(const float* __restrict__ in,
                        unsigned short* __restrict__ out, long n4) {
    long stride = (long)gridDim.x * blockDim.x;
    for (long i = (long)blockIdx.x * blockDim.x + threadIdx.x; i < n4; i += stride) {
        float4 v = *(const float4*)(in + i * 4);
        ushort4 o;
        o.x = f32_to_bf16(v.x); o.y = f32_to_bf16(v.y);
        o.z = f32_to_bf16(v.z); o.w = f32_to_bf16(v.w);
        *(ushort4*)(out + i * 4) = o;
    }
}

// ---- convert + transpose + interleave: in [H][F] fp32 -> wcat rows bf16 ----
// f-column f of `in` goes to wcat row ((f>>4)<<5) + (f&15) + off (off=0 gate,
// 16 up): 16-col interleave matching the 16x16 MFMA epilogue pairing.
__global__ void cvt_tri(const float* __restrict__ in,
                        unsigned short* __restrict__ out, int off) {
    __shared__ float tile[64][65];
    int bh = blockIdx.x & 63;   // H/64 = 64
    int bf = blockIdx.x >> 6;   // F/64 = 224
    int t = threadIdx.x;
    int r16 = t >> 4;           // 0..15
    int c4 = (t & 15) * 4;      // 0..60
#pragma unroll
    for (int it = 0; it < 4; ++it) {
        int h = r16 + it * 16;
        float4 v = *(const float4*)(in + (size_t)(bh * 64 + h) * FF + bf * 64 + c4);
        tile[h][c4 + 0] = v.x; tile[h][c4 + 1] = v.y;
        tile[h][c4 + 2] = v.z; tile[h][c4 + 3] = v.w;
    }
    __syncthreads();
#pragma unroll
    for (int it = 0; it < 4; ++it) {
        int f = r16 + it * 16;
        int fg = bf * 64 + f;
        int row_out = ((fg >> 4) << 5) + (fg & 15) + off;
        ushort4 o;
        o.x = f32_to_bf16(tile[c4 + 0][f]);
        o.y = f32_to_bf16(tile[c4 + 1][f]);
        o.z = f32_to_bf16(tile[c4 + 2][f]);
        o.w = f32_to_bf16(tile[c4 + 3][f]);
        *(ushort4*)(out + (size_t)row_out * HH + bh * 64 + c4) = o;
    }
}

// =================== 8-phase 256x256 GEMM core (BK=64, 8 waves) ============
// r15 = r12 verbatim (best measured: total 1286us, G1 787us / 1222 TF,
// MfmaUtil 58-60, 0 bank conflicts).  Ledger of excluded alternatives:
//  - 32x32x16 MFMA: fixed 4-cyc/ds_read_b128 conflict tax, swizzle-invariant
//    (r10/r11, SQ_LDS_BANK_CONFLICT bit-identical under 2 different swizzles).
//  - 2-barrier/K-step region schedule: null (r14); cross-K-step prefetch
//    without universal-drain+barrier: RACES (r13).
//  - fp8/MX/i8: excluded by error arithmetic (eps 2-3%/elem, K=4096,
//    5.9e7-sample absmax ~0.2-0.5 > 0.127 threshold).
// Schedule (r9-derived): hold af(32, in-place) + bfA(16, B0 resident) +
// bfB(16).  24 ds_reads/K-step balanced 8/4/8/4 (ph4 prefetches next
// K-step's B0 after the universal VMC8+BAR pair).  Snake
// (m0n0)->(m0n1)->(m1n1)->(m1n0).  Stage map (own buf, tile t+2):
// ph2<-A0+B0, ph3<-B1, ph4<-A1; vmcnt(8) at K-step end drains the buffer
// read next.  Compile-time CA/CB second-gload offsets (r10 spill fix).
// Registers: 64 held frag + acc 128 AGPR; arch cap 128 @ 2 waves/EU
// (one-time ~4-reg prologue spill = 8KB/block, harmless).
// Swizzle byte ^= ((row&6)<<4): pre-swizzled gload SOURCE + XOR on ds_read
// (LDS linear; conflict-free for the 16-row fragment pattern).

#define STG_A(BUF, SLOT, T) do {                                               \
    char* d_ = (char*)smem + (((BUF)*2 + (SLOT)) << 14) + tid * 16;            \
    GLOAD16(Abase + ((size_t)oA[SLOT] + (size_t)(T) * 128), d_);               \
    GLOAD16(Abase + ((size_t)oA[SLOT] + CA + (size_t)(T) * 128), d_ + 8192);   \
  } while (0)

#define STG_B(BUF, SLOT, T) do {                                               \
    char* d_ = (char*)smem + 65536 + (((BUF)*2 + (SLOT)) << 14) + tid * 16;    \
    GLOAD16(Bbase + ((size_t)oB[SLOT] + (size_t)(T) * 128), d_);               \
    GLOAD16(Bbase + ((size_t)oB[SLOT] + CB + (size_t)(T) * 128), d_ + 8192);   \
  } while (0)

#define READ_A(DST, BUF, MQ) do {                                              \
    const char* pA_ = (const char*)smem + (((BUF)*2 + (MQ)) << 14);            \
    _Pragma("unroll") for (int i_ = 0; i_ < 4; ++i_)                           \
    _Pragma("unroll") for (int k_ = 0; k_ < 2; ++k_)                           \
      DST[i_][k_] = *(const bf16x8*)(pA_ + ((((wr*64 + i_*16 + fr) << 7) + k_*64 + kg2) ^ lmask)); \
  } while (0)

#define READ_B(DST, BUF, NQ) do {                                              \
    const char* pB_ = (const char*)smem + 65536 + (((BUF)*2 + (NQ)) << 14);    \
    _Pragma("unroll") for (int j_ = 0; j_ < 2; ++j_)                           \
    _Pragma("unroll") for (int k_ = 0; k_ < 2; ++k_)                           \
      DST[j_][k_] = *(const bf16x8*)(pB_ + ((((wc*32 + j_*16 + fr) << 7) + k_*64 + kg2) ^ lmask)); \
  } while (0)

#define MFMA_Q(MQ, NQ, AF, BF)                                                 \
    _Pragma("unroll") for (int i_ = 0; i_ < 4; ++i_)                           \
    _Pragma("unroll") for (int j_ = 0; j_ < 2; ++j_)                           \
    _Pragma("unroll") for (int k_ = 0; k_ < 2; ++k_)                           \
      acc[MQ][i_][NQ][j_] = __builtin_amdgcn_mfma_f32_16x16x32_bf16(           \
          AF[i_][k_], BF[j_][k_], acc[MQ][i_][NQ][j_], 0, 0, 0)

#define BAR do {                                                               \
    asm volatile("" ::: "memory");                                             \
    __builtin_amdgcn_s_barrier();                                              \
    asm volatile("" ::: "memory");                                             \
  } while (0)

#define VMC8 asm volatile("s_waitcnt vmcnt(8)" ::: "memory")
#define VMC0 asm volatile("s_waitcnt vmcnt(0)" ::: "memory")

#define PHX(READS, STAGES, MQ, NQ, AF, BF, FENCE, POST) do {                   \
    READS;                                                                     \
    STAGES;                                                                    \
    __builtin_amdgcn_s_setprio(1);                                             \
    MFMA_Q(MQ, NQ, AF, BF);                                                    \
    __builtin_amdgcn_s_setprio(0);                                             \
    FENCE;                                                                     \
    POST;                                                                      \
    BAR;                                                                       \
  } while (0)

#define PH(READS, STAGES, MQ, NQ, AF, BF, FENCE)                               \
    PHX(READS, STAGES, MQ, NQ, AF, BF, FENCE, )

// One K-step (BK=64) on buffer BUF (other OB); stages own tile TS = t+2.
#define HALF_STG(BUF, OB, TS)                                                  \
    PH(READ_A(af, BUF, 0), , 0, 0, af, bfA, );                                 \
    PH(READ_B(bfB, BUF, 1), STG_A(BUF, 0, TS); STG_B(BUF, 0, TS), 0, 1, af, bfB, ); \
    PH(READ_A(af, BUF, 1), STG_B(BUF, 1, TS), 1, 1, af, bfB, );                \
    PHX(, STG_A(BUF, 1, TS), 1, 0, af, bfA, VMC8, READ_B(bfA, OB, 0));

#define HALF_T1(BUF, OB)                                                       \
    PH(READ_A(af, BUF, 0), , 0, 0, af, bfA, );                                 \
    PH(READ_B(bfB, BUF, 1), , 0, 1, af, bfB, );                                \
    PH(READ_A(af, BUF, 1), , 1, 1, af, bfB, );                                 \
    PHX(, , 1, 0, af, bfA, VMC0, READ_B(bfA, OB, 0));

#define HALF_T2(BUF)                                                           \
    PH(READ_A(af, BUF, 0), , 0, 0, af, bfA, );                                 \
    PH(READ_B(bfB, BUF, 1), , 0, 1, af, bfB, );                                \
    PH(READ_A(af, BUF, 1), , 1, 1, af, bfB, );                                 \
    PHX(, , 1, 0, af, bfA, , );

#define GEMM8_CORE(A_, LDA_, B_, LDB_, NT_)                                    \
  extern __shared__ char smem[];                                               \
  const char* const Abase = (const char*)(A_);                                 \
  const char* const Bbase = (const char*)(B_);                                 \
  const size_t CA = (size_t)(LDA_) * 256;                                      \
  const size_t CB = (size_t)(LDB_) * 256;                                      \
  const int tid = threadIdx.x;                                                 \
  const int lane = tid & 63;                                                   \
  const int wid = tid >> 6;                                                    \
  const int wr = wid >> 2;                                                     \
  const int wc = wid & 3;                                                      \
  const int fr = lane & 15;                                                    \
  const int kg2 = ((lane >> 4) & 3) << 4;                                      \
  const int lmask = (fr & 6) << 4;                                             \
  f32x4 acc[2][4][2][2];                                                       \
  _Pragma("unroll") for (int a_ = 0; a_ < 2; ++a_)                             \
  _Pragma("unroll") for (int b_ = 0; b_ < 4; ++b_)                             \
  _Pragma("unroll") for (int c_ = 0; c_ < 2; ++c_)                             \
  _Pragma("unroll") for (int d_ = 0; d_ < 2; ++d_)                             \
    acc[a_][b_][c_][d_] = (f32x4){0.f, 0.f, 0.f, 0.f};                         \
  bf16x8 af[4][2], bfA[2][2], bfB[2][2];                                       \
  unsigned int oA[2], oB[2];                                                   \
  {                                                                            \
    int d_ = tid * 16;                                                         \
    int p_ = d_ ^ (((d_ >> 8) & 3) << 5);                                      \
    int prow = p_ >> 7, pcol = (p_ & 127) >> 1;                                \
    _Pragma("unroll") for (int s_ = 0; s_ < 2; ++s_) {                         \
      int grA = m0 + s_ * 64 + (prow & 63);                                    \
      oA[s_] = (unsigned)((size_t)grA * (LDA_) + pcol) * 2u;                   \
      int grB = n0 + (prow >> 5) * 64 + s_ * 32 + (prow & 31);                 \
      oB[s_] = (unsigned)((size_t)grB * (LDB_) + pcol) * 2u;                   \
    }                                                                          \
  }                                                                            \
  /* prologue: both buffers' 4 slots (16 gloads); drain buf0's 8; preread */   \
  STG_A(0, 0, 0); STG_B(0, 0, 0); STG_B(0, 1, 0); STG_A(0, 1, 0);              \
  STG_A(1, 0, 1); STG_B(1, 0, 1); STG_B(1, 1, 1); STG_A(1, 1, 1);              \
  VMC8;                                                                        \
  __builtin_amdgcn_s_barrier();                                                \
  asm volatile("" ::: "memory");                                               \
  READ_B(bfA, 0, 0);                                                           \
  const int niter = (NT_) / 2;                                                 \
  for (int I = 0; I < niter - 1; ++I) {                                        \
    HALF_STG(0, 1, 2 * I + 2)                                                  \
    HALF_STG(1, 0, 2 * I + 3)                                                  \
  }                                                                            \
  HALF_T1(0, 1)                                                                \
  HALF_T2(1)

// ---------------- GEMM1: acc = Xb @ Wcat^T, fused SwiGLU epilogue ----------
__global__ __launch_bounds__(512)
__attribute__((amdgpu_waves_per_eu(1, 2))) void gemm_swiglu(
    const unsigned short* __restrict__ Xb,
    const unsigned short* __restrict__ Wcat,
    unsigned short* __restrict__ Act) {
    // tm-fast, NO XCD swizzle: consecutive bids share one n-column, spread
    // across XCDs by natural round-robin -> shared W window in L3.
    int lid = blockIdx.x;
    const int m0 = (lid & 15) * 256;
    const int n0 = (lid >> 4) * 256;

    GEMM8_CORE(Xb, HH, Wcat, HH, HH / 64)

    const int dm = ((lane >> 4) & 3) * 4;
    const int dn = lane & 15;
#pragma unroll
    for (int mq = 0; mq < 2; ++mq)
#pragma unroll
        for (int i = 0; i < 4; ++i)
#pragma unroll
            for (int nq = 0; nq < 2; ++nq) {
                int rowb = m0 + wr * 128 + mq * 64 + i * 16 + dm;
                int col = (n0 + wc * 64 + nq * 32) / 2 + dn;
                f32x4 g4 = acc[mq][i][nq][0];
                f32x4 u4 = acc[mq][i][nq][1];
#pragma unroll
                for (int r = 0; r < 4; ++r) {
                    float g = g4[r], u = u4[r];
                    float s = g * u / (1.0f + __expf(-g));
                    Act[(size_t)(rowb + r) * FF + col] = f32_to_bf16(s);
                }
            }
}

// ---------------- GEMM2: Out = Act @ W2b^T ----------------------------------
__global__ __launch_bounds__(512)
__attribute__((amdgpu_waves_per_eu(1, 2))) void gemm_down(
    const unsigned short* __restrict__ Act,
    const unsigned short* __restrict__ W2b,
    float* __restrict__ Out) {
    int lid = blockIdx.x;
    const int m0 = (lid & 15) * 256;
    const int n0 = (lid >> 4) * 256;

    GEMM8_CORE(Act, FF, W2b, FF, FF / 64)

    const int dm = ((lane >> 4) & 3) * 4;
    const int dn = lane & 15;
#pragma unroll
    for (int mq = 0; mq < 2; ++mq)
#pragma unroll
        for (int i = 0; i < 4; ++i)
#pragma unroll
            for (int nq = 0; nq < 2; ++nq)
#pragma unroll
                for (int j = 0; j < 2; ++j) {
                    int rowb = m0 + wr * 128 + mq * 64 + i * 16 + dm;
                    int col = n0 + wc * 64 + nq * 32 + j * 16 + dn;
                    f32x4 v = acc[mq][i][nq][j];
#pragma unroll
                    for (int r = 0; r < 4; ++r)
                        Out[(size_t)(rowb + r) * HH + col] = v[r];
                }
}

extern "C" void kernel_launch(void* const* d_in, const int* in_sizes, int n_in,
                              void* d_out, int out_size, void* d_ws, size_t ws_size,
                              hipStream_t stream) {
    const float* x  = (const float*)d_in[0];
    const float* w1 = (const float*)d_in[1];
    const float* v1 = (const float*)d_in[2];
    const float* w2 = (const float*)d_in[3];
    float* out = (float*)d_out;

    unsigned short* xb   = (unsigned short*)d_ws;               // [T][H]
    unsigned short* wcat = xb + (size_t)TT * HH;                // [2F][H]
    unsigned short* w2b  = wcat + (size_t)NCAT * HH;            // [H][F]
    unsigned short* act  = w2b + (size_t)HH * FF;               // [T][F]

    hipFuncSetAttribute((const void*)gemm_swiglu,
                        hipFuncAttributeMaxDynamicSharedMemorySize, 131072);
    hipFuncSetAttribute((const void*)gemm_down,
                        hipFuncAttributeMaxDynamicSharedMemorySize, 131072);

    cvt_lin<<<2048, 256, 0, stream>>>(x, xb, (long)TT * HH / 4);
    cvt_lin<<<2048, 256, 0, stream>>>(w2, w2b, (long)HH * FF / 4);
    cvt_tri<<<(HH / 64) * (FF / 64), 256, 0, stream>>>(w1, wcat, 0);
    cvt_tri<<<(HH / 64) * (FF / 64), 256, 0, stream>>>(v1, wcat, 16);

    gemm_swiglu<<<(TT / 256) * (NCAT / 256), 512, 131072, stream>>>(xb, wcat, act);
    gemm_down<<<(TT / 256) * (HH / 256), 512, 131072, stream>>>(act, w2b, out);
}